// Round 1
// baseline (1171.095 us; speedup 1.0000x reference)
//
#include <hip/hip_runtime.h>
#include <hip/hip_bf16.h>
#include <math.h>

#define HW 4096
#define SCALE 0.17677669529663687f

// ---------------- GEMM: Y[256][N] = W[256][256] @ X[256][N] + b ----------------
__global__ __launch_bounds__(256) void gemm256(const float* __restrict__ W,
                                               const float* __restrict__ bias,
                                               const float* __restrict__ X,
                                               float* __restrict__ Y, int N) {
  __shared__ float w_s[16][256];
  int tid = threadIdx.x;
  int o0 = (blockIdx.x >> 4) * 16;   // 16 o-tiles of 16
  int p0 = (blockIdx.x & 15) * 256;  // 16 p-tiles of 256
  #pragma unroll
  for (int i = 0; i < 16; ++i) w_s[i][tid] = W[(o0 + i) * 256 + tid];
  __syncthreads();
  int p = p0 + tid;
  float acc[16];
  #pragma unroll
  for (int i = 0; i < 16; ++i) acc[i] = 0.f;
  for (int c = 0; c < 256; ++c) {
    float xv = X[c * N + p];
    #pragma unroll
    for (int i = 0; i < 16; ++i) acc[i] += w_s[i][c] * xv;
  }
  #pragma unroll
  for (int i = 0; i < 16; ++i) Y[(o0 + i) * N + p] = acc[i] + bias[o0 + i];
}

// ---------------- depthwise 9x9 conv on q viewed as [4][64][64][64] ----------------
__global__ __launch_bounds__(256) void dwconv_kernel(const float* __restrict__ q,
                                                     const float* __restrict__ wdw,
                                                     const float* __restrict__ bdw,
                                                     float* __restrict__ o) {
  int lane = threadIdx.x & 63;   // x
  int wave = threadIdx.x >> 6;   // y sub
  int bid = blockIdx.x;          // g*64*16 + c*16 + y4
  int y4 = bid & 15; int c = (bid >> 4) & 63; int g = bid >> 10;
  int y = y4 * 4 + wave;
  int x = lane;
  const float* qc = q + (g * 64 + c) * HW;
  float acc = bdw[c];
  #pragma unroll
  for (int ky = 0; ky < 9; ++ky) {
    int yy = y + ky - 4;
    if (yy < 0 || yy > 63) continue;
    #pragma unroll
    for (int kx = 0; kx < 9; ++kx) {
      int xx = x + kx - 4;
      if (xx < 0 || xx > 63) continue;
      acc += wdw[c * 81 + ky * 9 + kx] * qc[yy * 64 + xx];
    }
  }
  o[(g * 64 + c) * HW + y * 64 + x] = acc;
}

// ---------------- LayerNorm(ch) + GELU + pointwise(2) + tanh + ref add -> pos ----------------
__global__ __launch_bounds__(256) void ln_offset_kernel(const float* __restrict__ o,
                                                        const float* __restrict__ ln_g,
                                                        const float* __restrict__ ln_b,
                                                        const float* __restrict__ wpw,
                                                        float* __restrict__ pos) {
  int wave = threadIdx.x >> 6;   // which x within block of 4
  int c = threadIdx.x & 63;      // channel
  int bid = blockIdx.x;          // g*64*16 + y*16 + xc
  int xc = bid & 15; int y = (bid >> 4) & 63; int g = bid >> 10;
  int x = xc * 4 + wave;
  int p = y * 64 + x;
  float v = o[(g * 64 + c) * HW + p];
  float s = v, s2 = v * v;
  #pragma unroll
  for (int m = 32; m; m >>= 1) { s += __shfl_xor(s, m); s2 += __shfl_xor(s2, m); }
  float mu = s * (1.f / 64.f);
  float var = s2 * (1.f / 64.f) - mu * mu;
  float nv = (v - mu) * rsqrtf(var + 1e-5f) * ln_g[c] + ln_b[c];
  // exact GELU
  nv = 0.5f * nv * (1.f + erff(nv * 0.70710678118654752f));
  float t0 = wpw[c] * nv, t1 = wpw[64 + c] * nv;
  #pragma unroll
  for (int m = 32; m; m >>= 1) { t0 += __shfl_xor(t0, m); t1 += __shfl_xor(t1, m); }
  if (c == 0) {
    float offy = tanhf(t0) * (2.0f / 64.0f);
    float offx = tanhf(t1) * (2.0f / 64.0f);
    float py = offy + (y + 0.5f) * (2.f / 64.f) - 1.f;
    float px = offx + (x + 0.5f) * (2.f / 64.f) - 1.f;
    pos[(g * HW + p) * 2 + 0] = py;
    pos[(g * HW + p) * 2 + 1] = px;
  }
}

// ---------------- bilinear sample of x at pos -> xs[256][4096] ----------------
__global__ __launch_bounds__(256) void sample_kernel(const float* __restrict__ x,
                                                     const float* __restrict__ pos,
                                                     float* __restrict__ xs) {
  int bid = blockIdx.x;  // g*16*4 + nt*4 + cc  (grid 256)
  int cc = bid & 3; int nt = (bid >> 2) & 15; int g = bid >> 6;
  int n = nt * 256 + threadIdx.x;
  float py = pos[(g * HW + n) * 2 + 0];
  float px = pos[(g * HW + n) * 2 + 1];
  float gx = (px + 1.f) * 31.5f;  // *0.5*(64-1)
  float gy = (py + 1.f) * 31.5f;
  float xf = floorf(gx), yf = floorf(gy);
  int xi = (int)xf, yi = (int)yf;
  float fx = gx - xf, fy = gy - yf;
  int x0c = min(max(xi, 0), 63), x1c = min(max(xi + 1, 0), 63);
  int y0c = min(max(yi, 0), 63), y1c = min(max(yi + 1, 0), 63);
  float wx0 = (xi >= 0 && xi <= 63) ? (1.f - fx) : 0.f;
  float wx1 = (xi + 1 >= 0 && xi + 1 <= 63) ? fx : 0.f;
  float wy0 = (yi >= 0 && yi <= 63) ? (1.f - fy) : 0.f;
  float wy1 = (yi + 1 >= 0 && yi + 1 <= 63) ? fy : 0.f;
  #pragma unroll 4
  for (int ci = 0; ci < 16; ++ci) {
    int c = cc * 16 + ci;
    const float* xp = x + (g * 64 + c) * HW;
    float vsum = wy0 * (wx0 * xp[y0c * 64 + x0c] + wx1 * xp[y0c * 64 + x1c]) +
                 wy1 * (wx0 * xp[y1c * 64 + x0c] + wx1 * xp[y1c * 64 + x1c]);
    xs[(g * 64 + c) * HW + n] = vsum;
  }
}

// ---------------- fused attention with RPE bias + online softmax ----------------
__global__ __launch_bounds__(256) void attn_kernel(const float* __restrict__ q,
                                                   const float* __restrict__ k,
                                                   const float* __restrict__ v,
                                                   const float* __restrict__ pos,
                                                   const float* __restrict__ rpe,
                                                   float* __restrict__ att) {
  __shared__ float rpe_s[127 * 127];
  __shared__ float q_s[32][33];
  __shared__ float k_s[32][33];
  __shared__ float v_s[32][33];
  __shared__ float pos_s[32][2];
  int tid = threadIdx.x;
  int h = blockIdx.x >> 7;        // 8 heads
  int mtile = blockIdx.x & 127;   // 128 query tiles of 32
  int m0 = mtile * 32;
  int g = h >> 1;
  const float* tab = rpe + h * 16129;
  for (int i = tid; i < 16129; i += 256) rpe_s[i] = tab[i];
  for (int i = tid; i < 1024; i += 256) {
    int c = i >> 5, m = i & 31;
    q_s[c][m] = q[(h * 32 + c) * HW + m0 + m];
  }
  int qrow = tid >> 3, nsub = tid & 7;  // 32 rows x 8 threads
  int mg = m0 + qrow;
  int ym = mg >> 6, xm = mg & 63;
  float qy = (ym + 0.5f) * (2.f / 64.f) - 1.f;
  float qx = (xm + 0.5f) * (2.f / 64.f) - 1.f;
  float acc[32];
  #pragma unroll
  for (int c = 0; c < 32; ++c) acc[c] = 0.f;
  float m_run = -3.0e38f, l_run = 0.f;
  __syncthreads();
  for (int nt = 0; nt < 128; ++nt) {
    int n0 = nt * 32;
    for (int i = tid; i < 1024; i += 256) {
      int c = i >> 5, n = i & 31;
      k_s[c][n] = k[(h * 32 + c) * HW + n0 + n];
      v_s[c][n] = v[(h * 32 + c) * HW + n0 + n];
    }
    if (tid < 64) {
      int n = tid >> 1, d = tid & 1;
      pos_s[n][d] = pos[(g * HW + n0 + n) * 2 + d];
    }
    __syncthreads();
    float s[4];
    #pragma unroll
    for (int j = 0; j < 4; ++j) s[j] = 0.f;
    for (int c = 0; c < 32; ++c) {
      float qv = q_s[c][qrow];
      #pragma unroll
      for (int j = 0; j < 4; ++j) s[j] += qv * k_s[c][nsub * 4 + j];
    }
    #pragma unroll
    for (int j = 0; j < 4; ++j) {
      int n = nsub * 4 + j;
      float py = pos_s[n][0], px = pos_s[n][1];
      float dy = (qy - py) * 0.5f, dx = (qx - px) * 0.5f;
      float gx = (dx + 1.f) * 63.f;  // *0.5*(127-1)
      float gy = (dy + 1.f) * 63.f;
      float xf = floorf(gx), yf = floorf(gy);
      int xi = (int)xf, yi = (int)yf;
      float fx = gx - xf, fy = gy - yf;
      int x0c = min(max(xi, 0), 126), x1c = min(max(xi + 1, 0), 126);
      int y0c = min(max(yi, 0), 126), y1c = min(max(yi + 1, 0), 126);
      float wx0 = (xi >= 0 && xi <= 126) ? (1.f - fx) : 0.f;
      float wx1 = (xi + 1 >= 0 && xi + 1 <= 126) ? fx : 0.f;
      float wy0 = (yi >= 0 && yi <= 126) ? (1.f - fy) : 0.f;
      float wy1 = (yi + 1 >= 0 && yi + 1 <= 126) ? fy : 0.f;
      float bias = wy0 * (wx0 * rpe_s[y0c * 127 + x0c] + wx1 * rpe_s[y0c * 127 + x1c]) +
                   wy1 * (wx0 * rpe_s[y1c * 127 + x0c] + wx1 * rpe_s[y1c * 127 + x1c]);
      s[j] = s[j] * SCALE + bias;
    }
    float tmax = fmaxf(fmaxf(s[0], s[1]), fmaxf(s[2], s[3]));
    tmax = fmaxf(tmax, __shfl_xor(tmax, 1));
    tmax = fmaxf(tmax, __shfl_xor(tmax, 2));
    tmax = fmaxf(tmax, __shfl_xor(tmax, 4));
    float mnew = fmaxf(m_run, tmax);
    float alpha = expf(m_run - mnew);
    float p[4]; float psum = 0.f;
    #pragma unroll
    for (int j = 0; j < 4; ++j) { p[j] = expf(s[j] - mnew); psum += p[j]; }
    psum += __shfl_xor(psum, 1);
    psum += __shfl_xor(psum, 2);
    psum += __shfl_xor(psum, 4);
    l_run = l_run * alpha + psum;
    m_run = mnew;
    #pragma unroll
    for (int c = 0; c < 32; ++c) {
      float a = acc[c] * alpha;
      #pragma unroll
      for (int j = 0; j < 4; ++j) a += p[j] * v_s[c][nsub * 4 + j];
      acc[c] = a;
    }
    __syncthreads();
  }
  // reduce the 8 partial accumulators per query row (lanes qrow*8+nsub within one wave)
  #pragma unroll
  for (int c = 0; c < 32; ++c) {
    float a = acc[c];
    a += __shfl_xor(a, 1);
    a += __shfl_xor(a, 2);
    a += __shfl_xor(a, 4);
    acc[c] = a;
  }
  if (nsub == 0) {
    float inv = 1.f / l_run;
    #pragma unroll
    for (int c = 0; c < 32; ++c) att[(h * 32 + c) * HW + m0 + qrow] = acc[c] * inv;
  }
}

extern "C" void kernel_launch(void* const* d_in, const int* in_sizes, int n_in,
                              void* d_out, int out_size, void* d_ws, size_t ws_size,
                              hipStream_t stream) {
  const float* x    = (const float*)d_in[0];
  const float* wq   = (const float*)d_in[1];
  const float* bq   = (const float*)d_in[2];
  const float* wk   = (const float*)d_in[3];
  const float* bk   = (const float*)d_in[4];
  const float* wv   = (const float*)d_in[5];
  const float* bv   = (const float*)d_in[6];
  const float* wdw  = (const float*)d_in[7];
  const float* bdw  = (const float*)d_in[8];
  const float* lng  = (const float*)d_in[9];
  const float* lnb  = (const float*)d_in[10];
  const float* wpw  = (const float*)d_in[11];
  const float* rpe  = (const float*)d_in[12];
  const float* wout = (const float*)d_in[13];
  const float* bout = (const float*)d_in[14];
  float* out = (float*)d_out;

  float* ws   = (float*)d_ws;
  float* q    = ws;                 // 1M floats
  float* xs   = q + (1 << 20);      // 1M floats (also depthwise output, then att)
  float* kbuf = xs + (1 << 20);     // 1M floats
  float* vbuf = kbuf + (1 << 20);   // 1M floats
  float* pos  = vbuf + (1 << 20);   // 32768 floats
  float* att  = xs;                 // reuse xs after k/v are formed

  gemm256<<<256, 256, 0, stream>>>(wq, bq, x, q, HW);
  dwconv_kernel<<<4096, 256, 0, stream>>>(q, wdw, bdw, xs);      // xs holds conv out
  ln_offset_kernel<<<4096, 256, 0, stream>>>(xs, lng, lnb, wpw, pos);
  sample_kernel<<<256, 256, 0, stream>>>(x, pos, xs);            // xs now holds sampled x
  gemm256<<<256, 256, 0, stream>>>(wk, bk, xs, kbuf, HW);
  gemm256<<<256, 256, 0, stream>>>(wv, bv, xs, vbuf, HW);
  attn_kernel<<<1024, 256, 0, stream>>>(q, kbuf, vbuf, pos, rpe, att);
  gemm256<<<256, 256, 0, stream>>>(wout, bout, att, out, HW);
}

// Round 2
// 454.193 us; speedup vs baseline: 2.5784x; 2.5784x over previous
//
#include <hip/hip_runtime.h>
#include <hip/hip_bf16.h>
#include <math.h>

#define HW 4096
#define SCALE 0.17677669529663687f

typedef __attribute__((ext_vector_type(8))) short short8;
typedef __attribute__((ext_vector_type(4))) float f32x4;
typedef __attribute__((ext_vector_type(4))) unsigned int u32x4;

static __device__ __forceinline__ unsigned short bf16b(float f) {
  __hip_bfloat16 h = __float2bfloat16(f);
  return *reinterpret_cast<unsigned short*>(&h);
}

// ---- GEMM: Y[256][4096] = W @ X + b; optional f32 out, per-head-transposed bf16, flat bf16 ----
__global__ __launch_bounds__(256) void gemm256(const float* __restrict__ W,
                                               const float* __restrict__ bias,
                                               const float* __restrict__ X,
                                               float* __restrict__ Yf,
                                               unsigned short* __restrict__ Yt,
                                               unsigned short* __restrict__ Yv) {
  __shared__ float w_s[16][256];
  int tid = threadIdx.x;
  int o0 = (blockIdx.x >> 4) * 16;
  int p = (blockIdx.x & 15) * 256 + tid;
  #pragma unroll
  for (int i = 0; i < 16; ++i) w_s[i][tid] = W[(o0 + i) * 256 + tid];
  __syncthreads();
  float acc[16];
  #pragma unroll
  for (int i = 0; i < 16; ++i) acc[i] = 0.f;
  for (int c = 0; c < 256; ++c) {
    float xv = X[c * HW + p];
    #pragma unroll
    for (int i = 0; i < 16; ++i) acc[i] += w_s[i][c] * xv;
  }
  float r[16];
  #pragma unroll
  for (int i = 0; i < 16; ++i) r[i] = acc[i] + bias[o0 + i];
  if (Yf) {
    #pragma unroll
    for (int i = 0; i < 16; ++i) Yf[(o0 + i) * HW + p] = r[i];
  }
  if (Yt) {  // Yt[(h*4096+p)*32 + c], h=o>>5, c=o&31
    int h = o0 >> 5, c0 = o0 & 31;
    unsigned int pk[8];
    #pragma unroll
    for (int j = 0; j < 8; ++j)
      pk[j] = (unsigned int)bf16b(r[2 * j]) | ((unsigned int)bf16b(r[2 * j + 1]) << 16);
    unsigned int* dst = (unsigned int*)(Yt + ((size_t)(h * HW + p) * 32 + c0));
    u32x4 lo4 = {pk[0], pk[1], pk[2], pk[3]};
    u32x4 hi4 = {pk[4], pk[5], pk[6], pk[7]};
    *(u32x4*)dst = lo4;
    *(u32x4*)(dst + 4) = hi4;
  }
  if (Yv) {
    #pragma unroll
    for (int i = 0; i < 16; ++i) Yv[(o0 + i) * HW + p] = bf16b(r[i]);
  }
}

// ---- depthwise 9x9 conv ----
__global__ __launch_bounds__(256) void dwconv_kernel(const float* __restrict__ q,
                                                     const float* __restrict__ wdw,
                                                     const float* __restrict__ bdw,
                                                     float* __restrict__ o) {
  int lane = threadIdx.x & 63;
  int wave = threadIdx.x >> 6;
  int bid = blockIdx.x;
  int y4 = bid & 15; int c = (bid >> 4) & 63; int g = bid >> 10;
  int y = y4 * 4 + wave;
  int x = lane;
  const float* qc = q + (g * 64 + c) * HW;
  float acc = bdw[c];
  #pragma unroll
  for (int ky = 0; ky < 9; ++ky) {
    int yy = y + ky - 4;
    if (yy < 0 || yy > 63) continue;
    #pragma unroll
    for (int kx = 0; kx < 9; ++kx) {
      int xx = x + kx - 4;
      if (xx < 0 || xx > 63) continue;
      acc += wdw[c * 81 + ky * 9 + kx] * qc[yy * 64 + xx];
    }
  }
  o[(g * 64 + c) * HW + y * 64 + x] = acc;
}

// ---- LN + GELU + pointwise + tanh -> pos (y,x) and cxy (cx,cy) ----
__global__ __launch_bounds__(256) void ln_offset_kernel(const float* __restrict__ o,
                                                        const float* __restrict__ ln_g,
                                                        const float* __restrict__ ln_b,
                                                        const float* __restrict__ wpw,
                                                        float* __restrict__ pos,
                                                        float* __restrict__ cxy) {
  int wave = threadIdx.x >> 6;
  int c = threadIdx.x & 63;
  int bid = blockIdx.x;
  int xc = bid & 15; int y = (bid >> 4) & 63; int g = bid >> 10;
  int x = xc * 4 + wave;
  int p = y * 64 + x;
  float v = o[(g * 64 + c) * HW + p];
  float s = v, s2 = v * v;
  #pragma unroll
  for (int m = 32; m; m >>= 1) { s += __shfl_xor(s, m); s2 += __shfl_xor(s2, m); }
  float mu = s * (1.f / 64.f);
  float var = s2 * (1.f / 64.f) - mu * mu;
  float nv = (v - mu) * rsqrtf(var + 1e-5f) * ln_g[c] + ln_b[c];
  nv = 0.5f * nv * (1.f + erff(nv * 0.70710678118654752f));
  float t0 = wpw[c] * nv, t1 = wpw[64 + c] * nv;
  #pragma unroll
  for (int m = 32; m; m >>= 1) { t0 += __shfl_xor(t0, m); t1 += __shfl_xor(t1, m); }
  if (c == 0) {
    float offy = tanhf(t0) * (2.0f / 64.0f);
    float offx = tanhf(t1) * (2.0f / 64.0f);
    float py = offy + (y + 0.5f) * (2.f / 64.f) - 1.f;
    float px = offx + (x + 0.5f) * (2.f / 64.f) - 1.f;
    pos[(g * HW + p) * 2 + 0] = py;
    pos[(g * HW + p) * 2 + 1] = px;
    cxy[(g * HW + p) * 2 + 0] = 63.0f - 31.5f * px;  // gx = ex_m + cx_n
    cxy[(g * HW + p) * 2 + 1] = 63.0f - 31.5f * py;  // gy = ey_m + cy_n
  }
}

// ---- bilinear sample of x at pos -> xs[256][4096] ----
__global__ __launch_bounds__(256) void sample_kernel(const float* __restrict__ x,
                                                     const float* __restrict__ pos,
                                                     float* __restrict__ xs) {
  int bid = blockIdx.x;
  int cc = bid & 3; int nt = (bid >> 2) & 15; int g = bid >> 6;
  int n = nt * 256 + threadIdx.x;
  float py = pos[(g * HW + n) * 2 + 0];
  float px = pos[(g * HW + n) * 2 + 1];
  float gx = (px + 1.f) * 31.5f;
  float gy = (py + 1.f) * 31.5f;
  float xf = floorf(gx), yf = floorf(gy);
  int xi = (int)xf, yi = (int)yf;
  float fx = gx - xf, fy = gy - yf;
  int x0c = min(max(xi, 0), 63), x1c = min(max(xi + 1, 0), 63);
  int y0c = min(max(yi, 0), 63), y1c = min(max(yi + 1, 0), 63);
  float wx0 = ((unsigned)xi <= 63u) ? (1.f - fx) : 0.f;
  float wx1 = ((unsigned)(xi + 1) <= 63u) ? fx : 0.f;
  float wy0 = ((unsigned)yi <= 63u) ? (1.f - fy) : 0.f;
  float wy1 = ((unsigned)(yi + 1) <= 63u) ? fy : 0.f;
  #pragma unroll 4
  for (int ci = 0; ci < 16; ++ci) {
    int c = cc * 16 + ci;
    const float* xp = x + (g * 64 + c) * HW;
    float vsum = wy0 * (wx0 * xp[y0c * 64 + x0c] + wx1 * xp[y0c * 64 + x1c]) +
                 wy1 * (wx0 * xp[y1c * 64 + x0c] + wx1 * xp[y1c * 64 + x1c]);
    xs[(g * 64 + c) * HW + n] = vsum;
  }
}

// ---- fused attention: MFMA qk/pv + RPE bilinear bias + online softmax ----
// Block: 4 waves share one 16-query tile; waves split n-tiles (interleaved); LDS merge.
__global__ __launch_bounds__(256) void attn_kernel(const unsigned short* __restrict__ qt,
                                                   const unsigned short* __restrict__ kt,
                                                   const unsigned short* __restrict__ vbuf,
                                                   const float* __restrict__ cxy,
                                                   const float* __restrict__ rpe,
                                                   float* __restrict__ att) {
  __shared__ __align__(16) float P_lds[4][16][36];
  __shared__ float red_m[4][16];
  __shared__ float red_l[4][16];
  __shared__ float red_acc[4][32][16];

  int tid = threadIdx.x;
  int w = tid >> 6;
  int l = tid & 63;
  int lm = l & 15;   // column: query m (S^T) / output m
  int lg = l >> 4;   // lane group
  int h = blockIdx.x >> 8;
  int mt = blockIdx.x & 255;
  int m0 = mt * 16;
  int m = m0 + lm;
  int xm = m & 63, ym = m >> 6;
  float ex = (xm + 0.5f) * (63.0f / 64.0f) - 31.5f;
  float ey = (ym + 0.5f) * (63.0f / 64.0f) - 31.5f;
  const float* tab = rpe + h * 16129;
  const float* cbase = cxy + (size_t)(h >> 1) * HW * 2;

  // Q fragment (B operand): lane holds Q_t[h][m][8*lg + j]
  short8 qf = *(const short8*)(qt + ((size_t)(h * HW + m) * 32 + 8 * lg));

  f32x4 oA = {0.f, 0.f, 0.f, 0.f};  // O^T rows c=0..15 (4*lg+r), col m
  f32x4 oB = {0.f, 0.f, 0.f, 0.f};  // rows c=16..31
  float m_run = -3.0e38f, l_run = 0.f;

  for (int it = 0; it < 32; ++it) {
    int n0 = (it * 4 + w) * 32;
    // K fragments (A operand of S^T = K.Q): A[n_local][c]
    short8 ka = *(const short8*)(kt + ((size_t)(h * HW + n0 + lm) * 32 + 8 * lg));
    short8 kb = *(const short8*)(kt + ((size_t)(h * HW + n0 + 16 + lm) * 32 + 8 * lg));
    f32x4 z = {0.f, 0.f, 0.f, 0.f};
    f32x4 s0 = __builtin_amdgcn_mfma_f32_16x16x32_bf16(ka, qf, z, 0, 0, 0);
    f32x4 s1 = __builtin_amdgcn_mfma_f32_16x16x32_bf16(kb, qf, z, 0, 0, 0);
    // V fragments (A operand of O^T = V.P^T): A[c_local][n]
    short8 va = *(const short8*)(vbuf + ((size_t)(h * 32 + lm) * HW + n0 + 8 * lg));
    short8 vB = *(const short8*)(vbuf + ((size_t)(h * 32 + 16 + lm) * HW + n0 + 8 * lg));

    float sv[8];
    #pragma unroll
    for (int t = 0; t < 2; ++t) {
      #pragma unroll
      for (int r = 0; r < 4; ++r) {
        int nl = 16 * t + 4 * lg + r;
        float2 cc = *(const float2*)(cbase + (size_t)(n0 + nl) * 2);
        float gx = ex + cc.x, gy = ey + cc.y;
        float xf = floorf(gx), yf = floorf(gy);
        float fx = gx - xf, fy = gy - yf;
        int xi = (int)xf, yi = (int)yf;
        int x0 = min(max(xi, 0), 126), x1 = min(max(xi + 1, 0), 126);
        int y0 = min(max(yi, 0), 126), y1 = min(max(yi + 1, 0), 126);
        float wx0 = ((unsigned)xi <= 126u) ? (1.f - fx) : 0.f;
        float wx1 = ((unsigned)(xi + 1) <= 126u) ? fx : 0.f;
        float wy0 = ((unsigned)yi <= 126u) ? (1.f - fy) : 0.f;
        float wy1 = ((unsigned)(yi + 1) <= 126u) ? fy : 0.f;
        const float* r0p = tab + y0 * 127;
        const float* r1p = tab + y1 * 127;
        float b = wy0 * (wx0 * r0p[x0] + wx1 * r0p[x1]) +
                  wy1 * (wx0 * r1p[x0] + wx1 * r1p[x1]);
        float qk = (t == 0) ? s0[r] : s1[r];
        sv[t * 4 + r] = qk * SCALE + b;
      }
    }
    // column (per-m) softmax over this 32-n tile
    float tmax = sv[0];
    #pragma unroll
    for (int i = 1; i < 8; ++i) tmax = fmaxf(tmax, sv[i]);
    tmax = fmaxf(tmax, __shfl_xor(tmax, 16));
    tmax = fmaxf(tmax, __shfl_xor(tmax, 32));
    float mnew = fmaxf(m_run, tmax);
    float alpha = __expf(m_run - mnew);
    float pv[8]; float psum = 0.f;
    #pragma unroll
    for (int i = 0; i < 8; ++i) { pv[i] = __expf(sv[i] - mnew); psum += pv[i]; }
    psum += __shfl_xor(psum, 16);
    psum += __shfl_xor(psum, 32);
    l_run = l_run * alpha + psum;
    m_run = mnew;
    oA *= alpha;
    oB *= alpha;
    // P round-trip through per-wave LDS: C-layout [m][n_local] -> B-fragment layout
    f32x4 w0 = {pv[0], pv[1], pv[2], pv[3]};
    f32x4 w1 = {pv[4], pv[5], pv[6], pv[7]};
    *(f32x4*)&P_lds[w][lm][4 * lg] = w0;
    *(f32x4*)&P_lds[w][lm][16 + 4 * lg] = w1;
    f32x4 p0 = *(f32x4*)&P_lds[w][lm][8 * lg];
    f32x4 p1 = *(f32x4*)&P_lds[w][lm][8 * lg + 4];
    short8 pf;
    pf[0] = (short)bf16b(p0[0]); pf[1] = (short)bf16b(p0[1]);
    pf[2] = (short)bf16b(p0[2]); pf[3] = (short)bf16b(p0[3]);
    pf[4] = (short)bf16b(p1[0]); pf[5] = (short)bf16b(p1[1]);
    pf[6] = (short)bf16b(p1[2]); pf[7] = (short)bf16b(p1[3]);
    oA = __builtin_amdgcn_mfma_f32_16x16x32_bf16(va, pf, oA, 0, 0, 0);
    oB = __builtin_amdgcn_mfma_f32_16x16x32_bf16(vB, pf, oB, 0, 0, 0);
  }

  // cross-wave merge
  if (lg == 0) { red_m[w][lm] = m_run; red_l[w][lm] = l_run; }
  #pragma unroll
  for (int r = 0; r < 4; ++r) {
    red_acc[w][4 * lg + r][lm] = oA[r];
    red_acc[w][16 + 4 * lg + r][lm] = oB[r];
  }
  __syncthreads();
  #pragma unroll
  for (int rep = 0; rep < 2; ++rep) {
    int idx = tid + rep * 256;
    int cl = idx >> 4, mm = idx & 15;
    float M = fmaxf(fmaxf(red_m[0][mm], red_m[1][mm]), fmaxf(red_m[2][mm], red_m[3][mm]));
    float lsum = 0.f, osum = 0.f;
    #pragma unroll
    for (int ww = 0; ww < 4; ++ww) {
      float e = __expf(red_m[ww][mm] - M);
      lsum += red_l[ww][mm] * e;
      osum += red_acc[ww][cl][mm] * e;
    }
    att[(size_t)(h * 32 + cl) * HW + m0 + mm] = osum / lsum;
  }
}

extern "C" void kernel_launch(void* const* d_in, const int* in_sizes, int n_in,
                              void* d_out, int out_size, void* d_ws, size_t ws_size,
                              hipStream_t stream) {
  const float* x    = (const float*)d_in[0];
  const float* wq   = (const float*)d_in[1];
  const float* bq   = (const float*)d_in[2];
  const float* wk   = (const float*)d_in[3];
  const float* bk   = (const float*)d_in[4];
  const float* wv   = (const float*)d_in[5];
  const float* bv   = (const float*)d_in[6];
  const float* wdw  = (const float*)d_in[7];
  const float* bdw  = (const float*)d_in[8];
  const float* lng  = (const float*)d_in[9];
  const float* lnb  = (const float*)d_in[10];
  const float* wpw  = (const float*)d_in[11];
  const float* rpe  = (const float*)d_in[12];
  const float* wout = (const float*)d_in[13];
  const float* bout = (const float*)d_in[14];
  float* out = (float*)d_out;

  float* ws = (float*)d_ws;
  float* q_f32 = ws;                                   // 4MB (later reused as xs)
  float* o_f32 = ws + (1 << 20);                       // 4MB (later reused as att)
  unsigned short* qt  = (unsigned short*)(ws + (2 << 20));  // 2MB
  unsigned short* ktp = qt + (1 << 20);                // 2MB
  unsigned short* vbp = ktp + (1 << 20);               // 2MB
  float* pos = (float*)(vbp + (1 << 20));              // 128KB
  float* cxy = pos + 32768;                            // 128KB

  gemm256<<<256, 256, 0, stream>>>(wq, bq, x, q_f32, qt, nullptr);
  dwconv_kernel<<<4096, 256, 0, stream>>>(q_f32, wdw, bdw, o_f32);
  ln_offset_kernel<<<4096, 256, 0, stream>>>(o_f32, lng, lnb, wpw, pos, cxy);
  sample_kernel<<<256, 256, 0, stream>>>(x, pos, q_f32);          // q_f32 := xs
  gemm256<<<256, 256, 0, stream>>>(wk, bk, q_f32, nullptr, ktp, nullptr);
  gemm256<<<256, 256, 0, stream>>>(wv, bv, q_f32, nullptr, nullptr, vbp);
  attn_kernel<<<2048, 256, 0, stream>>>(qt, ktp, vbp, cxy, rpe, o_f32);  // o_f32 := att
  gemm256<<<256, 256, 0, stream>>>(wout, bout, o_f32, out, nullptr, nullptr);
}